// Round 4
// baseline (803.244 us; speedup 1.0000x reference)
//
#include <hip/hip_runtime.h>

// GRAPHEDX forward — fp32 v4: per-graph block groups (8 blocks/graph) with
// device-scope atomic group barriers. Whole forward = 1 main dispatch.
// graph = blockIdx%48 -> a graph's 8 blocks share an XCD (round-robin map).

constexpr int kB = 48, kNM = 20, kNP = 190, kIters = 20;
constexpr float kInvT = 100.0f;
constexpr int kGB   = 8;              // blocks per graph (power of 2!)
constexpr int kNBLK = kB * kGB;       // 384  (<= 512 co-resident guaranteed)
constexpr int kNTHR = 256;

struct KP {
    const float *nf, *ef, *qadj, *cadj;
    const float *enc_nw, *enc_nb, *enc_ew, *enc_eb;
    const float *msg_w1, *msg_b1, *msg_w2, *msg_b2;
    const float *upd_w1, *upd_b1, *upd_w2, *upd_b2;
    const float *sink_w1, *sink_b1, *sink_w2, *sink_b2;
    const float *lrl_w1, *lrl_b1, *lrl_w2, *lrl_b2;
    const int *from_idx, *to_idx;
    float *out;
    float *h, *ee, *agg, *Hq, *Hc, *tq, *tc, *P, *Eq, *Ec;
    int *bar_cnt, *bar_gen;
};

__device__ __forceinline__ void pair_sd(int p, int& s, int& d) {
    int row = 0, rem = p;
    #pragma unroll
    for (int r = 0; r < 19; ++r) {
        int len = 19 - r;
        if (rem < len) { row = r; break; }
        rem -= len;
    }
    s = row; d = row + 1 + rem;
}

// wave-wide broadcast of lane k's value
__device__ __forceinline__ float bc(float v, int k) {
    return __int_as_float(__builtin_amdgcn_readlane(__float_as_int(v), k));
}

// 8-block group barrier: monotonic arrival counter + generation.
__device__ __forceinline__ void gbar(int* cnt, int* gen) {
    __syncthreads();                       // all block stores reach L2 (waitcnt+barrier)
    if (threadIdx.x == 0) {
        __threadfence();                   // release: flush XCD L2 to coherent point
        int g = atomicAdd(gen, 0);
        int old = atomicAdd(cnt, 1);
        if (((old + 1) & (kGB - 1)) == 0) {
            atomicAdd(gen, 1);
        } else {
            while (atomicAdd(gen, 0) == g) __builtin_amdgcn_s_sleep(2);
        }
        __threadfence();                   // acquire: invalidate stale L1/L2
    }
    __syncthreads();
}

__global__ void k_init(int* bar) {
    if (threadIdx.x < 2 * kB) bar[threadIdx.x] = 0;
}

__global__ void __launch_bounds__(kNTHR, 2) k_mega(KP p) {
    __shared__ float smem[400];                 // sinkhorn la / final Ps
    __shared__ unsigned char spsh[192], dpsh[192];

    const int b    = blockIdx.x % kB;           // graph id (group shares XCD)
    const int gb   = blockIdx.x / kB;           // 0..7 within group
    const int lane = threadIdx.x & 63;
    const int w    = threadIdx.x >> 6;
    const int gwave = gb * 4 + w;               // 0..31 within group
    const int gtid  = gb * kNTHR + threadIdx.x; // 0..2047 within group
    int* cnt = p.bar_cnt + b;
    int* gen = p.bar_gen + b;

    if (threadIdx.x < 192) {
        int s = 0, d = 0;
        if (threadIdx.x < kNP) pair_sd(threadIdx.x, s, d);
        spsh[threadIdx.x] = (unsigned char)s;
        dpsh[threadIdx.x] = (unsigned char)d;
    }

    // ---- P0: encoders + zero agg + zero out ----
    for (int i = gtid; i < 36 * 32; i += kGB * kNTHR) {
        int n = i >> 5, c = i & 31;
        const float* row = p.nf + (b * 36 + n) * 16;
        float acc = p.enc_nb[c];
        #pragma unroll
        for (int k = 0; k < 16; ++k) acc = fmaf(row[k], p.enc_nw[k * 32 + c], acc);
        p.h[(b * 36 + n) * 32 + c] = acc;
    }
    for (int i = gtid; i < 140 * 16; i += kGB * kNTHR) {
        int le = i >> 4, c = i & 15;
        int e = b * 140 + le;                   // edges are row-concat: b*140+le
        const float* row = p.ef + e * 8;
        float acc = p.enc_eb[c];
        #pragma unroll
        for (int k = 0; k < 8; ++k) acc = fmaf(row[k], p.enc_ew[k * 16 + c], acc);
        p.ee[e * 16 + c] = acc;
    }
    for (int i = gtid; i < 36 * 64; i += kGB * kNTHR) p.agg[b * 36 * 64 + i] = 0.f;
    if (gtid == 0) p.out[b] = 0.f;
    gbar(cnt, gen);

    // ---- prop: 5 x (msg ; upd) ----
    for (int r = 0; r < 5; ++r) {
        // msg: 140 edges = 28 quints over 32 waves (one pass)
        if (gwave < 28) {
            int t5 = gwave;
            int toj[5]; float xa[5], xb[5], acc[5];
            #pragma unroll
            for (int j = 0; j < 5; ++j) {
                int e = b * 140 + t5 * 5 + j;
                int fr = p.from_idx[e]; toj[j] = p.to_idx[e];
                xa[j] = p.h[(lane < 32 ? fr : toj[j]) * 32 + (lane & 31)];
                xb[j] = p.ee[e * 16 + (lane & 15)];
                acc[j] = p.msg_b1[lane];
            }
            #pragma unroll
            for (int k = 0; k < 64; ++k) {
                float w1k = p.msg_w1[k * 64 + lane];
                #pragma unroll
                for (int j = 0; j < 5; ++j) acc[j] = fmaf(bc(xa[j], k), w1k, acc[j]);
            }
            #pragma unroll
            for (int k = 0; k < 16; ++k) {
                float w1k = p.msg_w1[(64 + k) * 64 + lane];
                #pragma unroll
                for (int j = 0; j < 5; ++j) acc[j] = fmaf(bc(xb[j], k), w1k, acc[j]);
            }
            float o[5];
            #pragma unroll
            for (int j = 0; j < 5; ++j) { acc[j] = fmaxf(acc[j], 0.f); o[j] = p.msg_b2[lane]; }
            #pragma unroll
            for (int k = 0; k < 64; ++k) {
                float w2k = p.msg_w2[k * 64 + lane];
                #pragma unroll
                for (int j = 0; j < 5; ++j) o[j] = fmaf(bc(acc[j], k), w2k, o[j]);
            }
            #pragma unroll
            for (int j = 0; j < 5; ++j) atomicAdd(&p.agg[toj[j] * 64 + lane], o[j]);
        }
        gbar(cnt, gen);
        // upd: 36 nodes over 32 waves
        for (int n = gwave; n < 36; n += 32) {
            int gn = b * 36 + n;
            float xa = p.agg[gn * 64 + lane];
            p.agg[gn * 64 + lane] = 0.f;        // re-zero for next round
            float xb = p.h[gn * 32 + (lane & 31)];
            float acc = p.upd_b1[lane];
            #pragma unroll
            for (int k = 0; k < 64; ++k) acc = fmaf(bc(xa, k), p.upd_w1[k * 64 + lane], acc);
            #pragma unroll
            for (int k = 0; k < 32; ++k) acc = fmaf(bc(xb, k), p.upd_w1[(64 + k) * 64 + lane], acc);
            acc = fmaxf(acc, 0.f);
            float o = p.upd_b2[lane & 31];
            #pragma unroll
            for (int k = 0; k < 64; ++k) o = fmaf(bc(acc, k), p.upd_w2[k * 32 + (lane & 31)], o);
            if (lane < 32) p.h[gn * 32 + lane] += o;
        }
        gbar(cnt, gen);
    }

    // ---- P11: Hq/Hc + sink t-vectors (40 wave-tasks) ----
    for (int id = gwave; id < 40; id += 32) {
        int side = id >= 20, i = id % 20;
        float v = 0.f;
        if (lane < 32) {
            if (!side)           v = p.h[(b * 36 + i) * 32 + lane];
            else if (i < 16)     v = p.h[(b * 36 + 20 + i) * 32 + lane];
            (side ? p.Hc : p.Hq)[(b * 20 + i) * 32 + lane] = v;
        }
        int t = lane < 20 ? lane : 0;
        float acc = p.sink_b1[t];
        #pragma unroll
        for (int k = 0; k < 32; ++k) acc = fmaf(bc(v, k), p.sink_w1[k * 20 + t], acc);
        acc = fmaxf(acc, 0.f);
        float o = p.sink_b2[t];
        #pragma unroll
        for (int k = 0; k < 20; ++k) o = fmaf(bc(acc, k), p.sink_w2[k * 20 + t], o);
        if (lane < 20) (side ? p.tc : p.tq)[(b * 20 + i) * 20 + lane] = o;
    }
    gbar(cnt, gen);

    // ---- P12: sinkhorn+node_align (wave 0)  ||  edge_emb (waves 1..31) ----
    if (gwave == 0) {
        volatile float* la = smem;
        for (int idx = lane; idx < 400; idx += 64) {
            int i = idx / 20, j = idx % 20;
            const float* A = p.tq + (b * 20 + i) * 20;
            const float* C = p.tc + (b * 20 + j) * 20;
            float c = 0.f;
            #pragma unroll
            for (int k = 0; k < 20; ++k) c += fabsf(A[k] - C[k]);
            la[idx] = -c * kInvT;
        }
        for (int it = 0; it < kIters; ++it) {
            if (lane < 20) {
                float m = -3.0e38f, s = 0.f;
                #pragma unroll
                for (int j = 0; j < 20; ++j) m = fmaxf(m, la[lane * 20 + j]);
                #pragma unroll
                for (int j = 0; j < 20; ++j) s += __expf(la[lane * 20 + j] - m);
                float l = m + __logf(s);
                #pragma unroll
                for (int j = 0; j < 20; ++j) la[lane * 20 + j] -= l;
            }
            if (lane < 20) {
                float m = -3.0e38f, s = 0.f;
                #pragma unroll
                for (int i = 0; i < 20; ++i) m = fmaxf(m, la[i * 20 + lane]);
                #pragma unroll
                for (int i = 0; i < 20; ++i) s += __expf(la[i * 20 + lane] - m);
                float l = m + __logf(s);
                #pragma unroll
                for (int i = 0; i < 20; ++i) la[i * 20 + lane] -= l;
            }
        }
        for (int idx = lane; idx < 400; idx += 64) p.P[b * 400 + idx] = __expf(la[idx]);
        float part = 0.f;
        if (lane < 20) {
            float pr4 = __expf(la[lane * 20 + 16]) + __expf(la[lane * 20 + 17])
                      + __expf(la[lane * 20 + 18]) + __expf(la[lane * 20 + 19]);
            float l1 = 0.f;
            const float* hq = p.Hq + (b * 20 + lane) * 32;
            #pragma unroll
            for (int k = 0; k < 32; ++k) l1 += fabsf(hq[k]);
            part = pr4 * l1;
        }
        #pragma unroll
        for (int off = 32; off; off >>= 1) part += __shfl_down(part, off, 64);
        if (lane == 0) atomicAdd(&p.out[b], part);
    } else {
        for (int id = gwave - 1; id < 2 * kNP; id += 31) {
            int side = id >= kNP, pp = id % kNP;
            int s = spsh[pp], d = dpsh[pp];
            const float* H = side ? p.Hc : p.Hq;
            float xa = (lane < 32) ? H[(b * 20 + s) * 32 + lane]
                                   : H[(b * 20 + d) * 32 + (lane - 32)];
            float ev = (side ? p.cadj : p.qadj)[b * 400 + s * 20 + d];
            float af = p.lrl_b1[lane], ab = af;
            #pragma unroll
            for (int k = 0; k < 64; ++k) {
                float w1k = p.lrl_w1[k * 64 + lane];
                af = fmaf(bc(xa, k),      w1k, af);
                ab = fmaf(bc(xa, k ^ 32), w1k, ab);
            }
            float w1e = p.lrl_w1[64 * 64 + lane];
            af = fmaf(ev, w1e, af);
            ab = fmaf(ev, w1e, ab);
            float hid = fmaxf(af, 0.f) + fmaxf(ab, 0.f);
            float o = 2.f * p.lrl_b2[lane];
            #pragma unroll
            for (int k = 0; k < 64; ++k) o = fmaf(bc(hid, k), p.lrl_w2[k * 64 + lane], o);
            (side ? p.Ec : p.Eq)[(b * kNP + pp) * 64 + lane] = o;
        }
    }
    gbar(cnt, gen);

    // ---- P13: edge_align. lanes = feature d; q-tile of 32 in regs; p strided ----
    for (int i = threadIdx.x; i < 400; i += kNTHR) smem[i] = p.P[b * 400 + i];
    __syncthreads();
    int l31 = lane & 31;
    float a0 = 0.f, a1 = 0.f, a2 = 0.f, a3 = 0.f;
    for (int qt = 0; qt < 6; ++qt) {
        int q = qt * 32 + l31;
        bool qv = q < kNP;
        int sq = spsh[qv ? q : 0], dq = dpsh[qv ? q : 0];
        float acv = qv ? p.cadj[b * 400 + sq * 20 + dq] : 0.f;
        float ec[32];
        #pragma unroll
        for (int j = 0; j < 32; ++j) {
            int qq = qt * 32 + j;
            ec[j] = (qq < kNP) ? p.Ec[(b * kNP + qq) * 64 + lane] : 0.f;
        }
        for (int pp = gwave; pp < kNP; pp += 32) {
            int sp = spsh[pp], dp = dpsh[pp];
            float aq = p.qadj[b * 400 + sp * 20 + dp];
            float eT = smem[sp * 20 + sq] * smem[dp * 20 + dq]
                     + smem[sp * 20 + dq] * smem[dp * 20 + sq];
            float wqv = qv ? ((aq > 0.5f) ? (1.f - acv) : acv) * eT : 0.f;
            float eqv = p.Eq[(b * kNP + pp) * 64 + lane];
            #pragma unroll
            for (int j = 0; j < 32; j += 4) {
                a0 = fmaf(bc(wqv, j + 0), fabsf(eqv - ec[j + 0]), a0);
                a1 = fmaf(bc(wqv, j + 1), fabsf(eqv - ec[j + 1]), a1);
                a2 = fmaf(bc(wqv, j + 2), fabsf(eqv - ec[j + 2]), a2);
                a3 = fmaf(bc(wqv, j + 3), fabsf(eqv - ec[j + 3]), a3);
            }
        }
    }
    float partial = (a0 + a1) + (a2 + a3);
    #pragma unroll
    for (int off = 32; off; off >>= 1) partial += __shfl_down(partial, off, 64);
    if (lane == 0) atomicAdd(&p.out[b], partial);
}

extern "C" void kernel_launch(void* const* d_in, const int* in_sizes, int n_in,
                              void* d_out, int out_size, void* d_ws, size_t ws_size,
                              hipStream_t stream) {
    auto f = [&](int i) { return (const float*)d_in[i]; };
    float* ws = (float*)d_ws;
    KP kp;
    kp.nf = f(0);  kp.ef = f(1);  kp.qadj = f(2);  kp.cadj = f(3);
    kp.enc_nw = f(4);  kp.enc_nb = f(5);  kp.enc_ew = f(6);  kp.enc_eb = f(7);
    kp.msg_w1 = f(8);  kp.msg_b1 = f(9);  kp.msg_w2 = f(10); kp.msg_b2 = f(11);
    kp.upd_w1 = f(12); kp.upd_b1 = f(13); kp.upd_w2 = f(14); kp.upd_b2 = f(15);
    kp.sink_w1 = f(16); kp.sink_b1 = f(17); kp.sink_w2 = f(18); kp.sink_b2 = f(19);
    kp.lrl_w1 = f(20); kp.lrl_b1 = f(21); kp.lrl_w2 = f(22); kp.lrl_b2 = f(23);
    kp.from_idx = (const int*)d_in[24];
    kp.to_idx   = (const int*)d_in[25];
    kp.out = (float*)d_out;
    kp.h   = ws;                    // 55296
    kp.ee  = kp.h   + 55296;        // 107520
    kp.agg = kp.ee  + 107520;       // 110592
    kp.Hq  = kp.agg + 110592;       // 30720
    kp.Hc  = kp.Hq  + 30720;        // 30720
    kp.tq  = kp.Hc  + 30720;        // 19200
    kp.tc  = kp.tq  + 19200;        // 19200
    kp.P   = kp.tc  + 19200;        // 19200
    kp.Eq  = kp.P   + 19200;        // 583680
    kp.Ec  = kp.Eq  + 583680;       // 583680
    int* bar = (int*)(kp.Ec + 583680);
    kp.bar_cnt = bar;
    kp.bar_gen = bar + kB;

    k_init<<<1, 128, 0, stream>>>(bar);
    k_mega<<<kNBLK, kNTHR, 0, stream>>>(kp);
}

// Round 5
// 206.384 us; speedup vs baseline: 3.8920x; 3.8920x over previous
//
#include <hip/hip_runtime.h>

// GRAPHEDX forward — fp32 v5: proven v2 pipeline, k_final despill (ec[32] regs),
// encoders+zeroing fused. 15 dispatches.

constexpr int kB    = 48;
constexpr int kNM   = 20;    // NMAX
constexpr int kD    = 32;
constexpr int kNP   = 190;   // triu pairs
constexpr int kNTOT = 1728;
constexpr int kIters = 20;
constexpr float kInvT = 100.0f;

// triu_indices(20,1) row-major: p -> (s,d), s<d
__device__ __forceinline__ void pair_sd(int p, int& s, int& d) {
    int row = 0, rem = p;
    #pragma unroll
    for (int r = 0; r < 19; ++r) {
        int len = 19 - r;
        if (rem < len) { row = r; break; }
        rem -= len;
    }
    s = row; d = row + 1 + rem;
}

// wave-wide broadcast of lane k's value
__device__ __forceinline__ float bc(float v, int k) {
    return __int_as_float(__builtin_amdgcn_readlane(__float_as_int(v), k));
}

// ---------------- fused encoders + zeroing ----------------
__global__ void k_enc(const float* __restrict__ nf, const float* __restrict__ nw,
                      const float* __restrict__ nb, const float* __restrict__ ef,
                      const float* __restrict__ ew, const float* __restrict__ eb,
                      float* __restrict__ h, float* __restrict__ ee,
                      float* __restrict__ agg, float* __restrict__ out) {
    int tid = blockIdx.x * 256 + threadIdx.x;
    int stride = gridDim.x * 256;
    for (int i = tid; i < kNTOT * 32; i += stride) {
        int n = i >> 5, c = i & 31;
        float acc = nb[c];
        const float* row = nf + n * 16;
        #pragma unroll
        for (int k = 0; k < 16; ++k) acc = fmaf(row[k], nw[k * 32 + c], acc);
        h[i] = acc;
    }
    for (int i = tid; i < 6720 * 16; i += stride) {
        int n = i >> 4, c = i & 15;
        float acc = eb[c];
        const float* row = ef + n * 8;
        #pragma unroll
        for (int k = 0; k < 8; ++k) acc = fmaf(row[k], ew[k * 16 + c], acc);
        ee[i] = acc;
    }
    for (int i = tid; i < kNTOT * 64; i += stride) agg[i] = 0.f;
    if (tid < kB) out[tid] = 0.f;
}

// ---------------- message + scatter (v2 verbatim) ----------------
__global__ void k_msg(const float* __restrict__ h, const float* __restrict__ ee,
                      const int* __restrict__ fidx, const int* __restrict__ tidx,
                      const float* __restrict__ w1, const float* __restrict__ b1,
                      const float* __restrict__ w2, const float* __restrict__ b2,
                      float* __restrict__ agg) {
    __shared__ float xs[4][80];
    __shared__ float hs[4][64];
    int w = threadIdx.x >> 6, lane = threadIdx.x & 63;
    int e = blockIdx.x * 4 + w;                        // 6720 edges, 1680 blocks
    int from = fidx[e], to = tidx[e];
    if (lane < 32) xs[w][lane] = h[from * kD + lane];
    else           xs[w][lane] = h[to * kD + (lane - 32)];
    if (lane < 16) xs[w][64 + lane] = ee[e * 16 + lane];
    __syncthreads();
    float acc = b1[lane];
    #pragma unroll 8
    for (int k = 0; k < 80; ++k) acc += xs[w][k] * w1[k * 64 + lane];
    hs[w][lane] = fmaxf(acc, 0.f);
    __syncthreads();
    float o = b2[lane];
    #pragma unroll 8
    for (int k = 0; k < 64; ++k) o += hs[w][k] * w2[k * 64 + lane];
    atomicAdd(&agg[to * 64 + lane], o);
}

// ---------------- node update (v2 verbatim) ----------------
__global__ void k_upd(float* __restrict__ h, float* __restrict__ agg,
                      const float* __restrict__ w1, const float* __restrict__ b1,
                      const float* __restrict__ w2, const float* __restrict__ b2) {
    __shared__ float xs[4][96];
    __shared__ float hs[4][64];
    int w = threadIdx.x >> 6, lane = threadIdx.x & 63;
    int n = blockIdx.x * 4 + w;                        // 1728 nodes, 432 blocks
    xs[w][lane] = agg[n * 64 + lane];
    agg[n * 64 + lane] = 0.f;                          // zero for next prop round
    if (lane < 32) xs[w][64 + lane] = h[n * kD + lane];
    __syncthreads();
    float acc = b1[lane];
    #pragma unroll 8
    for (int k = 0; k < 96; ++k) acc += xs[w][k] * w1[k * 64 + lane];
    hs[w][lane] = fmaxf(acc, 0.f);
    __syncthreads();
    if (lane < 32) {
        float o = b2[lane];
        #pragma unroll 8
        for (int k = 0; k < 64; ++k) o += hs[w][k] * w2[k * 32 + lane];
        h[n * kD + lane] += o;
    }
}

// ---------------- build Hq/Hc + sink t-vectors (v2 verbatim) ----------------
__global__ void k_sink_t(const float* __restrict__ h,
                         const float* __restrict__ w1, const float* __restrict__ b1,
                         const float* __restrict__ w2, const float* __restrict__ b2,
                         float* __restrict__ Hq, float* __restrict__ Hc,
                         float* __restrict__ tq, float* __restrict__ tc) {
    __shared__ float xs[4][32];
    __shared__ float hs[4][20];
    int w = threadIdx.x >> 6, lane = threadIdx.x & 63;
    int id = blockIdx.x * 4 + w;                       // 1920 tasks, 480 blocks
    int side = id / (kB * kNM);
    int rem  = id % (kB * kNM);
    int b = rem / kNM, i = rem % kNM;
    if (lane < 32) {
        float v;
        if (side == 0) v = h[(b * 36 + i) * kD + lane];
        else           v = (i < 16) ? h[(b * 36 + 20 + i) * kD + lane] : 0.f;
        (side ? Hc : Hq)[(b * kNM + i) * kD + lane] = v;
        xs[w][lane] = v;
    }
    __syncthreads();
    if (lane < kNM) {
        float acc = b1[lane];
        #pragma unroll
        for (int k = 0; k < kD; ++k) acc += xs[w][k] * w1[k * kNM + lane];
        hs[w][lane] = fmaxf(acc, 0.f);
    }
    __syncthreads();
    if (lane < kNM) {
        float o = b2[lane];
        #pragma unroll
        for (int k = 0; k < kNM; ++k) o += hs[w][k] * w2[k * kNM + lane];
        (side ? tc : tq)[(b * kNM + i) * kNM + lane] = o;
    }
}

// ---------------- cost + Sinkhorn + node_align (v2 verbatim) ----------------
__global__ void k_sinkhorn(const float* __restrict__ tq, const float* __restrict__ tc,
                           const float* __restrict__ Hq,
                           float* __restrict__ P, float* __restrict__ out) {
    __shared__ float la[400], A[400], C[400];
    int b = blockIdx.x, t = threadIdx.x;               // 48 blocks x 64 threads
    for (int idx = t; idx < 400; idx += 64) { A[idx] = tq[b * 400 + idx]; C[idx] = tc[b * 400 + idx]; }
    __syncthreads();
    for (int pr = t; pr < 400; pr += 64) {
        int i = pr / 20, j = pr % 20;
        float c = 0.f;
        #pragma unroll
        for (int k = 0; k < 20; ++k) c += fabsf(A[i * 20 + k] - C[j * 20 + k]);
        la[pr] = -c * kInvT;
    }
    __syncthreads();
    for (int it = 0; it < kIters; ++it) {
        if (t < 20) {
            float m = -3.0e38f;
            #pragma unroll
            for (int j = 0; j < 20; ++j) m = fmaxf(m, la[t * 20 + j]);
            float s = 0.f;
            #pragma unroll
            for (int j = 0; j < 20; ++j) s += expf(la[t * 20 + j] - m);
            float l = m + logf(s);
            #pragma unroll
            for (int j = 0; j < 20; ++j) la[t * 20 + j] -= l;
        }
        __syncthreads();
        if (t < 20) {
            float m = -3.0e38f;
            #pragma unroll
            for (int i = 0; i < 20; ++i) m = fmaxf(m, la[i * 20 + t]);
            float s = 0.f;
            #pragma unroll
            for (int i = 0; i < 20; ++i) s += expf(la[i * 20 + t] - m);
            float l = m + logf(s);
            #pragma unroll
            for (int i = 0; i < 20; ++i) la[i * 20 + t] -= l;
        }
        __syncthreads();
    }
    for (int idx = t; idx < 400; idx += 64) P[b * 400 + idx] = expf(la[idx]);
    float part = 0.f;
    if (t < 20) {
        float pr = 0.f;
        #pragma unroll
        for (int j = 16; j < 20; ++j) pr += expf(la[t * 20 + j]);
        float l1 = 0.f;
        #pragma unroll
        for (int k = 0; k < 32; ++k) l1 += fabsf(Hq[(b * 20 + t) * 32 + k]);
        part = pr * l1;
    }
    #pragma unroll
    for (int off = 32; off; off >>= 1) part += __shfl_down(part, off, 64);
    if (t == 0) atomicAdd(&out[b], part);
}

// ---------------- edge embeddings (v2 verbatim) ----------------
__global__ void k_edge_emb(const float* __restrict__ Hq, const float* __restrict__ Hc,
                           const float* __restrict__ qadj, const float* __restrict__ cadj,
                           const float* __restrict__ w1, const float* __restrict__ b1,
                           const float* __restrict__ w2, const float* __restrict__ b2,
                           float* __restrict__ Eq, float* __restrict__ Ec) {
    __shared__ float xs[4][66];
    __shared__ float hs[4][64];
    int w = threadIdx.x >> 6, lane = threadIdx.x & 63;
    int id = blockIdx.x * 4 + w;                       // 18240 tasks, 4560 blocks
    int side = id / (kB * kNP);
    int rem  = id % (kB * kNP);
    int b = rem / kNP, p = rem % kNP;
    int sp, dp; pair_sd(p, sp, dp);
    const float* H   = side ? Hc : Hq;
    const float* adj = side ? cadj : qadj;
    if (lane < 32) xs[w][lane] = H[(b * kNM + sp) * kD + lane];
    else           xs[w][lane] = H[(b * kNM + dp) * kD + (lane - 32)];
    if (lane == 0) xs[w][64] = adj[b * 400 + sp * 20 + dp];
    __syncthreads();
    float af = b1[lane], ab = af;
    #pragma unroll 8
    for (int k = 0; k < 64; ++k) {
        float wk = w1[k * 64 + lane];
        af += xs[w][k] * wk;
        ab += xs[w][(k + 32) & 63] * wk;
    }
    {
        float wk = w1[64 * 64 + lane];
        float ev = xs[w][64];
        af += ev * wk; ab += ev * wk;
    }
    hs[w][lane] = fmaxf(af, 0.f) + fmaxf(ab, 0.f);
    __syncthreads();
    float o = 2.f * b2[lane];
    #pragma unroll 8
    for (int k = 0; k < 64; ++k) o += hs[w][k] * w2[k * 64 + lane];
    (side ? Ec : Eq)[(b * kNP + p) * 64 + lane] = o;
}

// ---------------- edge_align: block=(b,qtile of 32); lanes = feature dim ----------
__global__ void __launch_bounds__(256, 4)
k_final(const float* __restrict__ P, const float* __restrict__ Eq,
        const float* __restrict__ Ec, const float* __restrict__ qadj,
        const float* __restrict__ cadj, float* __restrict__ out) {
    __shared__ float Ps[400];
    __shared__ unsigned char spsh[192], dpsh[192];
    int b = blockIdx.x / 6, qt = blockIdx.x % 6;       // 288 blocks
    int t = threadIdx.x, w = t >> 6, lane = t & 63;
    if (t < 192) {
        int s = 0, d = 0;
        if (t < kNP) pair_sd(t, s, d);
        spsh[t] = (unsigned char)s;
        dpsh[t] = (unsigned char)d;
    }
    for (int i = t; i < 400; i += 256) Ps[i] = P[b * 400 + i];
    __syncthreads();

    int l31 = lane & 31;
    int q = qt * 32 + l31;
    bool qv = q < kNP;
    int sq = spsh[qv ? q : 0], dq = dpsh[qv ? q : 0];
    float acv = qv ? cadj[b * 400 + sq * 20 + dq] : 0.f;

    float ec[32];                                       // statically indexed -> regs
    #pragma unroll
    for (int j = 0; j < 32; ++j) {
        int qq = qt * 32 + j;
        ec[j] = (qq < kNP) ? Ec[(b * kNP + qq) * 64 + lane] : 0.f;
    }

    float a0 = 0.f, a1 = 0.f, a2 = 0.f, a3 = 0.f;
    for (int pp = w; pp < kNP; pp += 4) {
        int sp = spsh[pp], dp = dpsh[pp];
        float aq = qadj[b * 400 + sp * 20 + dp];
        float eT = Ps[sp * 20 + sq] * Ps[dp * 20 + dq]
                 + Ps[sp * 20 + dq] * Ps[dp * 20 + sq];
        float wqv = qv ? ((aq > 0.5f) ? (1.f - acv) : acv) * eT : 0.f;
        float eqv = Eq[(b * kNP + pp) * 64 + lane];
        #pragma unroll
        for (int j = 0; j < 32; j += 4) {
            a0 = fmaf(bc(wqv, j + 0), fabsf(eqv - ec[j + 0]), a0);
            a1 = fmaf(bc(wqv, j + 1), fabsf(eqv - ec[j + 1]), a1);
            a2 = fmaf(bc(wqv, j + 2), fabsf(eqv - ec[j + 2]), a2);
            a3 = fmaf(bc(wqv, j + 3), fabsf(eqv - ec[j + 3]), a3);
        }
    }
    float partial = (a0 + a1) + (a2 + a3);
    #pragma unroll
    for (int off = 32; off; off >>= 1) partial += __shfl_down(partial, off, 64);
    if (lane == 0) atomicAdd(&out[b], partial);
}

extern "C" void kernel_launch(void* const* d_in, const int* in_sizes, int n_in,
                              void* d_out, int out_size, void* d_ws, size_t ws_size,
                              hipStream_t stream) {
    auto f = [&](int i) { return (const float*)d_in[i]; };
    const float* nf   = f(0);
    const float* ef   = f(1);
    const float* qadj = f(2);
    const float* cadj = f(3);
    const int* from_idx = (const int*)d_in[24];
    const int* to_idx   = (const int*)d_in[25];
    float* out = (float*)d_out;

    float* ws  = (float*)d_ws;
    float* h   = ws;                       // 55296
    float* ee  = h   + 55296;              // 107520
    float* agg = ee  + 107520;             // 110592
    float* Hq  = agg + 110592;             // 30720
    float* Hc  = Hq  + 30720;              // 30720
    float* tq  = Hc  + 30720;              // 19200
    float* tc  = tq  + 19200;              // 19200
    float* P   = tc  + 19200;              // 19200
    float* Eq  = P   + 19200;              // 583680
    float* Ec  = Eq  + 583680;             // 583680

    k_enc<<<432, 256, 0, stream>>>(nf, f(4), f(5), ef, f(6), f(7), h, ee, agg, out);
    for (int it = 0; it < 5; ++it) {
        k_msg<<<1680, 256, 0, stream>>>(h, ee, from_idx, to_idx,
                                        f(8), f(9), f(10), f(11), agg);
        k_upd<<<432, 256, 0, stream>>>(h, agg, f(12), f(13), f(14), f(15));
    }
    k_sink_t<<<480, 256, 0, stream>>>(h, f(16), f(17), f(18), f(19), Hq, Hc, tq, tc);
    k_sinkhorn<<<48, 64, 0, stream>>>(tq, tc, Hq, P, out);
    k_edge_emb<<<4560, 256, 0, stream>>>(Hq, Hc, qadj, cadj,
                                         f(20), f(21), f(22), f(23), Eq, Ec);
    k_final<<<288, 256, 0, stream>>>(P, Eq, Ec, qadj, cadj, out);
}

// Round 6
// 177.954 us; speedup vs baseline: 4.5138x; 1.1598x over previous
//
#include <hip/hip_runtime.h>

// GRAPHEDX forward — fp32 v6: v5 + register-resident Sinkhorn
// (lane=row, in-register LSE trees, padded LDS transpose).

constexpr int kB    = 48;
constexpr int kNM   = 20;    // NMAX
constexpr int kD    = 32;
constexpr int kNP   = 190;   // triu pairs
constexpr int kNTOT = 1728;
constexpr int kIters = 20;
constexpr float kInvT = 100.0f;

// triu_indices(20,1) row-major: p -> (s,d), s<d
__device__ __forceinline__ void pair_sd(int p, int& s, int& d) {
    int row = 0, rem = p;
    #pragma unroll
    for (int r = 0; r < 19; ++r) {
        int len = 19 - r;
        if (rem < len) { row = r; break; }
        rem -= len;
    }
    s = row; d = row + 1 + rem;
}

// wave-wide broadcast of lane k's value
__device__ __forceinline__ float bc(float v, int k) {
    return __int_as_float(__builtin_amdgcn_readlane(__float_as_int(v), k));
}

// in-register LSE over 20 values: r[k] -= log(sum_k exp(r[k]))
__device__ __forceinline__ void lse20(float (&r)[20]) {
    float m01 = fmaxf(r[0], r[1]),  m23 = fmaxf(r[2], r[3]),
          m45 = fmaxf(r[4], r[5]),  m67 = fmaxf(r[6], r[7]),
          m89 = fmaxf(r[8], r[9]),  mab = fmaxf(r[10], r[11]),
          mcd = fmaxf(r[12], r[13]), mef = fmaxf(r[14], r[15]),
          mgh = fmaxf(r[16], r[17]), mij = fmaxf(r[18], r[19]);
    float n0 = fmaxf(m01, m23), n1 = fmaxf(m45, m67), n2 = fmaxf(m89, mab),
          n3 = fmaxf(mcd, mef), n4 = fmaxf(mgh, mij);
    float m = fmaxf(fmaxf(fmaxf(n0, n1), fmaxf(n2, n3)), n4);
    float e[20];
    #pragma unroll
    for (int k = 0; k < 20; ++k) e[k] = __expf(r[k] - m);
    float s01 = e[0] + e[1],  s23 = e[2] + e[3],  s45 = e[4] + e[5],
          s67 = e[6] + e[7],  s89 = e[8] + e[9],  sab = e[10] + e[11],
          scd = e[12] + e[13], sef = e[14] + e[15], sgh = e[16] + e[17],
          sij = e[18] + e[19];
    float t0 = s01 + s23, t1 = s45 + s67, t2 = s89 + sab,
          t3 = scd + sef, t4 = sgh + sij;
    float s = ((t0 + t1) + (t2 + t3)) + t4;
    float l = m + __logf(s);
    #pragma unroll
    for (int k = 0; k < 20; ++k) r[k] -= l;
}

// ---------------- fused encoders + zeroing ----------------
__global__ void k_enc(const float* __restrict__ nf, const float* __restrict__ nw,
                      const float* __restrict__ nb, const float* __restrict__ ef,
                      const float* __restrict__ ew, const float* __restrict__ eb,
                      float* __restrict__ h, float* __restrict__ ee,
                      float* __restrict__ agg, float* __restrict__ out) {
    int tid = blockIdx.x * 256 + threadIdx.x;
    int stride = gridDim.x * 256;
    for (int i = tid; i < kNTOT * 32; i += stride) {
        int n = i >> 5, c = i & 31;
        float acc = nb[c];
        const float* row = nf + n * 16;
        #pragma unroll
        for (int k = 0; k < 16; ++k) acc = fmaf(row[k], nw[k * 32 + c], acc);
        h[i] = acc;
    }
    for (int i = tid; i < 6720 * 16; i += stride) {
        int n = i >> 4, c = i & 15;
        float acc = eb[c];
        const float* row = ef + n * 8;
        #pragma unroll
        for (int k = 0; k < 8; ++k) acc = fmaf(row[k], ew[k * 16 + c], acc);
        ee[i] = acc;
    }
    for (int i = tid; i < kNTOT * 64; i += stride) agg[i] = 0.f;
    if (tid < kB) out[tid] = 0.f;
}

// ---------------- message + scatter (v2 verbatim) ----------------
__global__ void k_msg(const float* __restrict__ h, const float* __restrict__ ee,
                      const int* __restrict__ fidx, const int* __restrict__ tidx,
                      const float* __restrict__ w1, const float* __restrict__ b1,
                      const float* __restrict__ w2, const float* __restrict__ b2,
                      float* __restrict__ agg) {
    __shared__ float xs[4][80];
    __shared__ float hs[4][64];
    int w = threadIdx.x >> 6, lane = threadIdx.x & 63;
    int e = blockIdx.x * 4 + w;                        // 6720 edges, 1680 blocks
    int from = fidx[e], to = tidx[e];
    if (lane < 32) xs[w][lane] = h[from * kD + lane];
    else           xs[w][lane] = h[to * kD + (lane - 32)];
    if (lane < 16) xs[w][64 + lane] = ee[e * 16 + lane];
    __syncthreads();
    float acc = b1[lane];
    #pragma unroll 8
    for (int k = 0; k < 80; ++k) acc += xs[w][k] * w1[k * 64 + lane];
    hs[w][lane] = fmaxf(acc, 0.f);
    __syncthreads();
    float o = b2[lane];
    #pragma unroll 8
    for (int k = 0; k < 64; ++k) o += hs[w][k] * w2[k * 64 + lane];
    atomicAdd(&agg[to * 64 + lane], o);
}

// ---------------- node update (v2 verbatim) ----------------
__global__ void k_upd(float* __restrict__ h, float* __restrict__ agg,
                      const float* __restrict__ w1, const float* __restrict__ b1,
                      const float* __restrict__ w2, const float* __restrict__ b2) {
    __shared__ float xs[4][96];
    __shared__ float hs[4][64];
    int w = threadIdx.x >> 6, lane = threadIdx.x & 63;
    int n = blockIdx.x * 4 + w;                        // 1728 nodes, 432 blocks
    xs[w][lane] = agg[n * 64 + lane];
    agg[n * 64 + lane] = 0.f;                          // zero for next prop round
    if (lane < 32) xs[w][64 + lane] = h[n * kD + lane];
    __syncthreads();
    float acc = b1[lane];
    #pragma unroll 8
    for (int k = 0; k < 96; ++k) acc += xs[w][k] * w1[k * 64 + lane];
    hs[w][lane] = fmaxf(acc, 0.f);
    __syncthreads();
    if (lane < 32) {
        float o = b2[lane];
        #pragma unroll 8
        for (int k = 0; k < 64; ++k) o += hs[w][k] * w2[k * 32 + lane];
        h[n * kD + lane] += o;
    }
}

// ---------------- build Hq/Hc + sink t-vectors (v2 verbatim) ----------------
__global__ void k_sink_t(const float* __restrict__ h,
                         const float* __restrict__ w1, const float* __restrict__ b1,
                         const float* __restrict__ w2, const float* __restrict__ b2,
                         float* __restrict__ Hq, float* __restrict__ Hc,
                         float* __restrict__ tq, float* __restrict__ tc) {
    __shared__ float xs[4][32];
    __shared__ float hs[4][20];
    int w = threadIdx.x >> 6, lane = threadIdx.x & 63;
    int id = blockIdx.x * 4 + w;                       // 1920 tasks, 480 blocks
    int side = id / (kB * kNM);
    int rem  = id % (kB * kNM);
    int b = rem / kNM, i = rem % kNM;
    if (lane < 32) {
        float v;
        if (side == 0) v = h[(b * 36 + i) * kD + lane];
        else           v = (i < 16) ? h[(b * 36 + 20 + i) * kD + lane] : 0.f;
        (side ? Hc : Hq)[(b * kNM + i) * kD + lane] = v;
        xs[w][lane] = v;
    }
    __syncthreads();
    if (lane < kNM) {
        float acc = b1[lane];
        #pragma unroll
        for (int k = 0; k < kD; ++k) acc += xs[w][k] * w1[k * kNM + lane];
        hs[w][lane] = fmaxf(acc, 0.f);
    }
    __syncthreads();
    if (lane < kNM) {
        float o = b2[lane];
        #pragma unroll
        for (int k = 0; k < kNM; ++k) o += hs[w][k] * w2[k * kNM + lane];
        (side ? tc : tq)[(b * kNM + i) * kNM + lane] = o;
    }
}

// ---------------- Sinkhorn: register-resident rows, LDS transpose ----------------
__global__ void k_sinkhorn(const float* __restrict__ tq, const float* __restrict__ tc,
                           const float* __restrict__ Hq,
                           float* __restrict__ P, float* __restrict__ out) {
    __shared__ float tcS[400];
    __shared__ float tr[20 * 21];                      // +1 pad: conflict-free T
    int b = blockIdx.x, lane = threadIdx.x;            // 48 blocks x 64 threads
    for (int i = lane; i < 400; i += 64) tcS[i] = tc[b * 400 + i];
    int i20 = lane < 20 ? lane : 0;
    float tqr[20];
    #pragma unroll
    for (int k = 0; k < 20; ++k) tqr[k] = tq[(b * 20 + i20) * 20 + k];
    __syncthreads();
    // r[j] = la[row=lane][j]
    float r[20];
    #pragma unroll
    for (int j = 0; j < 20; ++j) {
        float c = 0.f;
        #pragma unroll
        for (int k = 0; k < 20; ++k) c += fabsf(tqr[k] - tcS[j * 20 + k]);
        r[j] = -c * kInvT;
    }
    for (int it = 0; it < kIters; ++it) {
        lse20(r);                                      // row LSE (lane = row)
        if (lane < 20) {
            #pragma unroll
            for (int j = 0; j < 20; ++j) tr[lane * 21 + j] = r[j];
        }
        __syncthreads();
        if (lane < 20) {
            #pragma unroll
            for (int i = 0; i < 20; ++i) r[i] = tr[i * 21 + lane];
        }
        __syncthreads();
        lse20(r);                                      // col LSE (lane = col)
        if (lane < 20) {
            #pragma unroll
            for (int i = 0; i < 20; ++i) tr[i * 21 + lane] = r[i];
        }
        __syncthreads();
        if (lane < 20) {
            #pragma unroll
            for (int j = 0; j < 20; ++j) r[j] = tr[lane * 21 + j];
        }
        __syncthreads();
    }
    // P + node_align.  r = final la, lane = row.
    float part = 0.f;
    if (lane < 20) {
        float pv[20];
        #pragma unroll
        for (int j = 0; j < 20; ++j) pv[j] = __expf(r[j]);
        float* Pb = P + b * 400 + lane * 20;
        #pragma unroll
        for (int j = 0; j < 20; ++j) Pb[j] = pv[j];
        float pr4 = (pv[16] + pv[17]) + (pv[18] + pv[19]);
        float l1 = 0.f;
        const float* hq = Hq + (b * 20 + lane) * 32;
        #pragma unroll
        for (int k = 0; k < 32; ++k) l1 += fabsf(hq[k]);
        part = pr4 * l1;
    }
    #pragma unroll
    for (int off = 32; off; off >>= 1) part += __shfl_down(part, off, 64);
    if (lane == 0) atomicAdd(&out[b], part);
}

// ---------------- edge embeddings (v2 verbatim) ----------------
__global__ void k_edge_emb(const float* __restrict__ Hq, const float* __restrict__ Hc,
                           const float* __restrict__ qadj, const float* __restrict__ cadj,
                           const float* __restrict__ w1, const float* __restrict__ b1,
                           const float* __restrict__ w2, const float* __restrict__ b2,
                           float* __restrict__ Eq, float* __restrict__ Ec) {
    __shared__ float xs[4][66];
    __shared__ float hs[4][64];
    int w = threadIdx.x >> 6, lane = threadIdx.x & 63;
    int id = blockIdx.x * 4 + w;                       // 18240 tasks, 4560 blocks
    int side = id / (kB * kNP);
    int rem  = id % (kB * kNP);
    int b = rem / kNP, p = rem % kNP;
    int sp, dp; pair_sd(p, sp, dp);
    const float* H   = side ? Hc : Hq;
    const float* adj = side ? cadj : qadj;
    if (lane < 32) xs[w][lane] = H[(b * kNM + sp) * kD + lane];
    else           xs[w][lane] = H[(b * kNM + dp) * kD + (lane - 32)];
    if (lane == 0) xs[w][64] = adj[b * 400 + sp * 20 + dp];
    __syncthreads();
    float af = b1[lane], ab = af;
    #pragma unroll 8
    for (int k = 0; k < 64; ++k) {
        float wk = w1[k * 64 + lane];
        af += xs[w][k] * wk;
        ab += xs[w][(k + 32) & 63] * wk;
    }
    {
        float wk = w1[64 * 64 + lane];
        float ev = xs[w][64];
        af += ev * wk; ab += ev * wk;
    }
    hs[w][lane] = fmaxf(af, 0.f) + fmaxf(ab, 0.f);
    __syncthreads();
    float o = 2.f * b2[lane];
    #pragma unroll 8
    for (int k = 0; k < 64; ++k) o += hs[w][k] * w2[k * 64 + lane];
    (side ? Ec : Eq)[(b * kNP + p) * 64 + lane] = o;
}

// ---------------- edge_align: block=(b,qtile of 32); lanes = feature dim ----------
__global__ void __launch_bounds__(256, 4)
k_final(const float* __restrict__ P, const float* __restrict__ Eq,
        const float* __restrict__ Ec, const float* __restrict__ qadj,
        const float* __restrict__ cadj, float* __restrict__ out) {
    __shared__ float Ps[400];
    __shared__ unsigned char spsh[192], dpsh[192];
    int b = blockIdx.x / 6, qt = blockIdx.x % 6;       // 288 blocks
    int t = threadIdx.x, w = t >> 6, lane = t & 63;
    if (t < 192) {
        int s = 0, d = 0;
        if (t < kNP) pair_sd(t, s, d);
        spsh[t] = (unsigned char)s;
        dpsh[t] = (unsigned char)d;
    }
    for (int i = t; i < 400; i += 256) Ps[i] = P[b * 400 + i];
    __syncthreads();

    int l31 = lane & 31;
    int q = qt * 32 + l31;
    bool qv = q < kNP;
    int sq = spsh[qv ? q : 0], dq = dpsh[qv ? q : 0];
    float acv = qv ? cadj[b * 400 + sq * 20 + dq] : 0.f;

    float ec[32];                                       // statically indexed -> regs
    #pragma unroll
    for (int j = 0; j < 32; ++j) {
        int qq = qt * 32 + j;
        ec[j] = (qq < kNP) ? Ec[(b * kNP + qq) * 64 + lane] : 0.f;
    }

    float a0 = 0.f, a1 = 0.f, a2 = 0.f, a3 = 0.f;
    for (int pp = w; pp < kNP; pp += 4) {
        int sp = spsh[pp], dp = dpsh[pp];
        float aq = qadj[b * 400 + sp * 20 + dp];
        float eT = Ps[sp * 20 + sq] * Ps[dp * 20 + dq]
                 + Ps[sp * 20 + dq] * Ps[dp * 20 + sq];
        float wqv = qv ? ((aq > 0.5f) ? (1.f - acv) : acv) * eT : 0.f;
        float eqv = Eq[(b * kNP + pp) * 64 + lane];
        #pragma unroll
        for (int j = 0; j < 32; j += 4) {
            a0 = fmaf(bc(wqv, j + 0), fabsf(eqv - ec[j + 0]), a0);
            a1 = fmaf(bc(wqv, j + 1), fabsf(eqv - ec[j + 1]), a1);
            a2 = fmaf(bc(wqv, j + 2), fabsf(eqv - ec[j + 2]), a2);
            a3 = fmaf(bc(wqv, j + 3), fabsf(eqv - ec[j + 3]), a3);
        }
    }
    float partial = (a0 + a1) + (a2 + a3);
    #pragma unroll
    for (int off = 32; off; off >>= 1) partial += __shfl_down(partial, off, 64);
    if (lane == 0) atomicAdd(&out[b], partial);
}

extern "C" void kernel_launch(void* const* d_in, const int* in_sizes, int n_in,
                              void* d_out, int out_size, void* d_ws, size_t ws_size,
                              hipStream_t stream) {
    auto f = [&](int i) { return (const float*)d_in[i]; };
    const float* nf   = f(0);
    const float* ef   = f(1);
    const float* qadj = f(2);
    const float* cadj = f(3);
    const int* from_idx = (const int*)d_in[24];
    const int* to_idx   = (const int*)d_in[25];
    float* out = (float*)d_out;

    float* ws  = (float*)d_ws;
    float* h   = ws;                       // 55296
    float* ee  = h   + 55296;              // 107520
    float* agg = ee  + 107520;             // 110592
    float* Hq  = agg + 110592;             // 30720
    float* Hc  = Hq  + 30720;              // 30720
    float* tq  = Hc  + 30720;              // 19200
    float* tc  = tq  + 19200;              // 19200
    float* P   = tc  + 19200;              // 19200
    float* Eq  = P   + 19200;              // 583680
    float* Ec  = Eq  + 583680;             // 583680

    k_enc<<<432, 256, 0, stream>>>(nf, f(4), f(5), ef, f(6), f(7), h, ee, agg, out);
    for (int it = 0; it < 5; ++it) {
        k_msg<<<1680, 256, 0, stream>>>(h, ee, from_idx, to_idx,
                                        f(8), f(9), f(10), f(11), agg);
        k_upd<<<432, 256, 0, stream>>>(h, agg, f(12), f(13), f(14), f(15));
    }
    k_sink_t<<<480, 256, 0, stream>>>(h, f(16), f(17), f(18), f(19), Hq, Hc, tq, tc);
    k_sinkhorn<<<48, 64, 0, stream>>>(tq, tc, Hq, P, out);
    k_edge_emb<<<4560, 256, 0, stream>>>(Hq, Hc, qadj, cadj,
                                         f(20), f(21), f(22), f(23), Eq, Ec);
    k_final<<<288, 256, 0, stream>>>(P, Eq, Ec, qadj, cadj, out);
}